// Round 1
// baseline (2138.950 us; speedup 1.0000x reference)
//
#include <hip/hip_runtime.h>
#include <hip/hip_bf16.h>

// ---------------------------------------------------------------------------
// WinEncoderTransformer: 2-layer encoder with HiLo attention, MI355X gfx950
// Geometry: N=128 seq, B=1024 batch, C=256, rows R = N*B = 131072
// Row r <-> (bc = r>>7, hh = (r>>4)&7, ww = r&15)  [faithful to the reshape]
// ---------------------------------------------------------------------------

#define RT 131072ull
#define ATT_SCALE 0.17677669529663687f   // 32^-0.5

typedef float f32x4 __attribute__((ext_vector_type(4)));
typedef __bf16 bf16x8 __attribute__((ext_vector_type(8)));
typedef unsigned short u16x8 __attribute__((ext_vector_type(8)));

__device__ __forceinline__ unsigned short f2bf(float f) {
    unsigned int u = __float_as_uint(f);
    return (unsigned short)((u + 0x7FFFu + ((u >> 16) & 1u)) >> 16);  // RNE
}

// ---------------------------------------------------------------------------
// GEMM: C[M x N] = A[M x K] @ B[K x N] (+bias) (+relu), fp32 in/out,
// bf16 MFMA accumulate. BM=128, BN=64, BK=64, 256 threads (2x2 waves).
// LDS XOR-swizzled (byte ^= (row&7)<<4) so fragment ds_read_b128 is ~conflict-free.
// ---------------------------------------------------------------------------
template<bool BIAS, bool RELU>
__global__ __launch_bounds__(256) void gemm_bf16(
    const float* __restrict__ A, int lda,
    const float* __restrict__ Bw, int ldb,
    const float* __restrict__ bias,
    float* __restrict__ C, int ldc, int K)
{
    __shared__ __align__(16) char lds[(128 * 64 + 64 * 64) * 2];
    char* As = lds;                 // 128 rows x 128B (64 bf16), swizzled
    char* Bs = lds + 128 * 64 * 2;  // 64 n-rows x 128B (64 k bf16), swizzled

    const int tid = threadIdx.x;
    const size_t m0 = (size_t)blockIdx.x * 128;
    const int n0 = blockIdx.y * 64;

    const int w = tid >> 6, l = tid & 63;
    const int wm = w >> 1, wn = w & 1;
    const int lr = l & 15, lk = l >> 4;

    f32x4 acc[4][2] = {};

    for (int k0 = 0; k0 < K; k0 += 64) {
        // stage A tile: 1024 chunks of 8 fp32 -> 16B bf16 LDS stores
        #pragma unroll
        for (int i = 0; i < 4; ++i) {
            int cid = tid + i * 256;
            int row = cid >> 3, kc = cid & 7;
            const float* src = A + (m0 + (size_t)row) * lda + (k0 + kc * 8);
            f32x4 a0 = *(const f32x4*)src;
            f32x4 a1 = *(const f32x4*)(src + 4);
            union { u16x8 v; unsigned short s[8]; } t;
            #pragma unroll
            for (int j = 0; j < 4; ++j) { t.s[j] = f2bf(a0[j]); t.s[4 + j] = f2bf(a1[j]); }
            int byte = (row * 128 + kc * 16) ^ ((row & 7) << 4);
            *(u16x8*)(As + byte) = t.v;
        }
        // stage B tile transposed: Bs[n][k]
        #pragma unroll
        for (int i = 0; i < 4; ++i) {
            int fid = tid + i * 256;
            int kk = fid >> 4;
            int nn = (fid & 15) * 4;
            f32x4 bv = *(const f32x4*)(Bw + (size_t)(k0 + kk) * ldb + (n0 + nn));
            #pragma unroll
            for (int j = 0; j < 4; ++j) {
                int nr = nn + j;
                int byte = (nr * 128 + (kk >> 3) * 16 + (kk & 7) * 2) ^ ((nr & 7) << 4);
                *(unsigned short*)(Bs + byte) = f2bf(bv[j]);
            }
        }
        __syncthreads();
        #pragma unroll
        for (int kk = 0; kk < 2; ++kk) {
            bf16x8 bfr[2];
            #pragma unroll
            for (int nt = 0; nt < 2; ++nt) {
                int nr = wn * 32 + nt * 16 + lr;
                int byte = (nr * 128 + kk * 64 + lk * 16) ^ ((nr & 7) << 4);
                bfr[nt] = *(bf16x8*)(Bs + byte);
            }
            #pragma unroll
            for (int mt = 0; mt < 4; ++mt) {
                int ar = wm * 64 + mt * 16 + lr;
                int byte = (ar * 128 + kk * 64 + lk * 16) ^ ((ar & 7) << 4);
                bf16x8 afr = *(bf16x8*)(As + byte);
                acc[mt][0] = __builtin_amdgcn_mfma_f32_16x16x32_bf16(afr, bfr[0], acc[mt][0], 0, 0, 0);
                acc[mt][1] = __builtin_amdgcn_mfma_f32_16x16x32_bf16(afr, bfr[1], acc[mt][1], 0, 0, 0);
            }
        }
        __syncthreads();
    }
    // epilogue: C/D layout col=lane&15, row=(lane>>4)*4+j (m89-verified)
    #pragma unroll
    for (int mt = 0; mt < 4; ++mt) {
        #pragma unroll
        for (int nt = 0; nt < 2; ++nt) {
            int col = n0 + wn * 32 + nt * 16 + lr;
            float bv = BIAS ? bias[col] : 0.0f;
            #pragma unroll
            for (int j = 0; j < 4; ++j) {
                size_t row = m0 + (size_t)(wm * 64 + mt * 16 + lk * 4 + j);
                float v = acc[mt][nt][j] + bv;
                if (RELU) v = fmaxf(v, 0.0f);
                C[row * ldc + col] = v;
            }
        }
    }
}

// ---------------------------------------------------------------------------
// hifi: windowed 4-token attention. qkv row layout: [q(4h x 32) | k | v].
// One thread per (window, head, query). 524288 threads.
// ---------------------------------------------------------------------------
__global__ __launch_bounds__(256) void hifi_attn(const float* __restrict__ qkv,
                                                 float* __restrict__ o)
{
    int t = blockIdx.x * 256 + threadIdx.x;
    int wdw = t >> 4;
    int h = (t >> 2) & 3;
    int qi = t & 3;
    int bc = wdw >> 5, tw = wdw & 31;
    int rbase = bc * 128 + (tw >> 3) * 32 + (tw & 7) * 2;
    int qrow = rbase + (qi >> 1) * 16 + (qi & 1);

    const float* qp = qkv + (size_t)qrow * 384 + h * 32;
    f32x4 qv[8];
    #pragma unroll
    for (int i = 0; i < 8; ++i) qv[i] = *(const f32x4*)(qp + i * 4);

    float s[4];
    #pragma unroll
    for (int j = 0; j < 4; ++j) {
        int krow = rbase + (j >> 1) * 16 + (j & 1);
        const float* kp = qkv + (size_t)krow * 384 + 128 + h * 32;
        float d = 0.0f;
        #pragma unroll
        for (int i = 0; i < 8; ++i) {
            f32x4 kv4 = *(const f32x4*)(kp + i * 4);
            d += qv[i][0] * kv4[0] + qv[i][1] * kv4[1] + qv[i][2] * kv4[2] + qv[i][3] * kv4[3];
        }
        s[j] = d * ATT_SCALE;
    }
    float mx = fmaxf(fmaxf(s[0], s[1]), fmaxf(s[2], s[3]));
    float den = 0.0f;
    #pragma unroll
    for (int j = 0; j < 4; ++j) { s[j] = __expf(s[j] - mx); den += s[j]; }
    float inv = 1.0f / den;

    f32x4 ov[8] = {};
    #pragma unroll
    for (int j = 0; j < 4; ++j) {
        int vrow = rbase + (j >> 1) * 16 + (j & 1);
        const float* vp = qkv + (size_t)vrow * 384 + 256 + h * 32;
        float a = s[j] * inv;
        #pragma unroll
        for (int i = 0; i < 8; ++i) {
            f32x4 vv = *(const f32x4*)(vp + i * 4);
            ov[i] += vv * a;
        }
    }
    float* op = o + (size_t)qrow * 128 + h * 32;
    #pragma unroll
    for (int i = 0; i < 8; ++i) *(f32x4*)(op + i * 4) = ov[i];
}

// ---------------------------------------------------------------------------
// pool: xp[p][c] = mean of the 2x2 window's 4 rows
// ---------------------------------------------------------------------------
__global__ __launch_bounds__(256) void pool_kernel(const float* __restrict__ x,
                                                   float* __restrict__ xp)
{
    int id = blockIdx.x * 256 + threadIdx.x;   // p*64 + c4
    int p = id >> 6;
    int c = (id & 63) * 4;
    int bc = p >> 5, tw = p & 31;
    int rbase = bc * 128 + (tw >> 3) * 32 + (tw & 7) * 2;
    const float* x0 = x + (size_t)rbase * 256 + c;
    f32x4 v = (*(const f32x4*)x0 + *(const f32x4*)(x0 + 256) +
               *(const f32x4*)(x0 + 16 * 256) + *(const f32x4*)(x0 + 17 * 256)) * 0.25f;
    *(f32x4*)(xp + (size_t)p * 256 + c) = v;
}

// ---------------------------------------------------------------------------
// lofi: 128 queries vs 32 pooled keys per (bc, head). Block = 128 threads
// (one per query); k/v staged in LDS (broadcast reads, conflict-free).
// kv row layout: [k(4h x 32) | v(4h x 32)]
// ---------------------------------------------------------------------------
__global__ __launch_bounds__(128) void lofi_attn(const float* __restrict__ qb,
                                                 const float* __restrict__ kvb,
                                                 float* __restrict__ ob)
{
    __shared__ float ks[32][36];
    __shared__ float vs[32][36];
    int bc = blockIdx.x >> 2, h = blockIdx.x & 3;
    int tid = threadIdx.x;

    #pragma unroll
    for (int i = 0; i < 2; ++i) {
        int fid = tid + i * 128;              // 256 float4 per matrix
        int row = fid >> 3, cc = (fid & 7) * 4;
        const float* kp = kvb + (size_t)(bc * 32 + row) * 256 + h * 32 + cc;
        f32x4 kk = *(const f32x4*)kp;
        f32x4 vv = *(const f32x4*)(kp + 128);
        #pragma unroll
        for (int j = 0; j < 4; ++j) { ks[row][cc + j] = kk[j]; vs[row][cc + j] = vv[j]; }
    }

    const float* qp = qb + (size_t)(bc * 128 + tid) * 128 + h * 32;
    f32x4 qv[8];
    #pragma unroll
    for (int i = 0; i < 8; ++i) qv[i] = *(const f32x4*)(qp + i * 4);
    __syncthreads();

    float s[32];
    #pragma unroll
    for (int tk = 0; tk < 32; ++tk) {
        float d = 0.0f;
        #pragma unroll
        for (int i = 0; i < 32; ++i) d += qv[i >> 2][i & 3] * ks[tk][i];
        s[tk] = d * ATT_SCALE;
    }
    float mx = -1e30f;
    #pragma unroll
    for (int tk = 0; tk < 32; ++tk) mx = fmaxf(mx, s[tk]);
    float den = 0.0f;
    #pragma unroll
    for (int tk = 0; tk < 32; ++tk) { s[tk] = __expf(s[tk] - mx); den += s[tk]; }
    float inv = 1.0f / den;

    float outv[32] = {};
    #pragma unroll
    for (int tk = 0; tk < 32; ++tk) {
        float a = s[tk];
        #pragma unroll
        for (int i = 0; i < 32; ++i) outv[i] += a * vs[tk][i];
    }
    float* op = ob + (size_t)(bc * 128 + tid) * 128 + h * 32;
    #pragma unroll
    for (int i = 0; i < 8; ++i) {
        f32x4 v;
        #pragma unroll
        for (int j = 0; j < 4; ++j) v[j] = outv[i * 4 + j] * inv;
        *(f32x4*)(op + i * 4) = v;
    }
}

// ---------------------------------------------------------------------------
// add_ln: out = LN(x + a) row-wise over 256. One wave per row; a may be null.
// ---------------------------------------------------------------------------
__global__ __launch_bounds__(256) void add_ln(const float* __restrict__ x,
                                              const float* __restrict__ a,
                                              const float* __restrict__ g,
                                              const float* __restrict__ b,
                                              float* __restrict__ out)
{
    size_t r = (size_t)blockIdx.x * 4 + (threadIdx.x >> 6);
    int l = threadIdx.x & 63;
    f32x4 v = *(const f32x4*)(x + r * 256 + l * 4);
    if (a) v += *(const f32x4*)(a + r * 256 + l * 4);
    float s = v[0] + v[1] + v[2] + v[3];
    float sq = v[0] * v[0] + v[1] * v[1] + v[2] * v[2] + v[3] * v[3];
    #pragma unroll
    for (int off = 32; off > 0; off >>= 1) {
        s += __shfl_xor(s, off);
        sq += __shfl_xor(sq, off);
    }
    float mean = s * (1.0f / 256.0f);
    float var = sq * (1.0f / 256.0f) - mean * mean;
    float rstd = rsqrtf(var + 1e-5f);
    f32x4 gg = *(const f32x4*)(g + l * 4);
    f32x4 bb = *(const f32x4*)(b + l * 4);
    f32x4 o;
    #pragma unroll
    for (int j = 0; j < 4; ++j) o[j] = (v[j] - mean) * rstd * gg[j] + bb[j];
    *(f32x4*)(out + r * 256 + l * 4) = o;
}

// ---------------------------------------------------------------------------
extern "C" void kernel_launch(void* const* d_in, const int* in_sizes, int n_in,
                              void* d_out, int out_size, void* d_ws, size_t ws_size,
                              hipStream_t stream)
{
    (void)in_sizes; (void)n_in; (void)out_size; (void)ws_size;
    const float* tgt   = (const float*)d_in[0];
    const float* Wlq   = (const float*)d_in[1];
    const float* Wlkv  = (const float*)d_in[2];
    const float* Wlp   = (const float*)d_in[3];
    const float* blp   = (const float*)d_in[4];
    const float* Whqkv = (const float*)d_in[5];
    const float* Whp   = (const float*)d_in[6];
    const float* bhp   = (const float*)d_in[7];
    const float* W1    = (const float*)d_in[8];
    const float* b1    = (const float*)d_in[9];
    const float* W2    = (const float*)d_in[10];
    const float* b2    = (const float*)d_in[11];
    const float* ln1g  = (const float*)d_in[12];
    const float* ln1b  = (const float*)d_in[13];
    const float* ln2g  = (const float*)d_in[14];
    const float* ln2b  = (const float*)d_in[15];
    const float* lnfg  = (const float*)d_in[16];
    const float* lnfb  = (const float*)d_in[17];

    float* x   = (float*)d_out;         // activation lives in d_out
    float* wsf = (float*)d_ws;

    // workspace region layout (floats), lifetimes disjoint:
    //   [0 .. RT*512)  : qkvbuf(R*384)+obuf(R*128) -> qbuf/xp/kv -> hbuf(R*512)
    //   [RT*512 .. RT*512+RT*256) : abuf (attention/ffn output, R*256)
    float* qkvbuf = wsf;
    float* obuf   = wsf + RT * 384;
    float* qbuf   = wsf;
    float* xpbuf  = wsf + RT * 128;
    float* kvbuf  = wsf + RT * 128 + 32768ull * 256;
    float* hbuf   = wsf;
    float* abuf   = wsf + RT * 512;

    hipMemcpyAsync(x, tgt, RT * 256 * sizeof(float), hipMemcpyDeviceToDevice, stream);

    for (int i = 0; i < 2; ++i) {
        // 1. qkv = x @ Whqkv[i]                (R x 384)
        gemm_bf16<false, false><<<dim3(RT / 128, 6), 256, 0, stream>>>(
            x, 256, Whqkv + (size_t)i * 256 * 384, 384, nullptr, qkvbuf, 384, 256);
        // 2. hifi window attention -> obuf     (R x 128)
        hifi_attn<<<2048, 256, 0, stream>>>(qkvbuf, obuf);
        // 3. hi = obuf @ Whp[i] + bhp[i] -> abuf[:, 0:128]
        gemm_bf16<true, false><<<dim3(RT / 128, 2), 256, 0, stream>>>(
            obuf, 128, Whp + (size_t)i * 128 * 128, 128, bhp + (size_t)i * 128,
            abuf, 256, 128);
        // 4. q = x @ Wlq[i] -> qbuf            (R x 128)
        gemm_bf16<false, false><<<dim3(RT / 128, 2), 256, 0, stream>>>(
            x, 256, Wlq + (size_t)i * 256 * 128, 128, nullptr, qbuf, 128, 256);
        // 5. pooled xp                          (32768 x 256)
        pool_kernel<<<8192, 256, 0, stream>>>(x, xpbuf);
        // 6. kv = xp @ Wlkv[i] -> kvbuf        (32768 x 256)
        gemm_bf16<false, false><<<dim3(32768 / 128, 4), 256, 0, stream>>>(
            xpbuf, 256, Wlkv + (size_t)i * 256 * 256, 256, nullptr, kvbuf, 256, 256);
        // 7. lofi attention -> obuf            (R x 128)
        lofi_attn<<<4096, 128, 0, stream>>>(qbuf, kvbuf, obuf);
        // 8. lo = obuf @ Wlp[i] + blp[i] -> abuf[:, 128:256]
        gemm_bf16<true, false><<<dim3(RT / 128, 2), 256, 0, stream>>>(
            obuf, 128, Wlp + (size_t)i * 128 * 128, 128, blp + (size_t)i * 128,
            abuf + 128, 256, 128);
        // 9. x = LN(x + abuf)
        add_ln<<<RT / 4, 256, 0, stream>>>(x, abuf, ln1g + (size_t)i * 256,
                                           ln1b + (size_t)i * 256, x);
        // 10. h = relu(x @ W1[i] + b1[i])      (R x 512)
        gemm_bf16<true, true><<<dim3(RT / 128, 8), 256, 0, stream>>>(
            x, 256, W1 + (size_t)i * 256 * 512, 512, b1 + (size_t)i * 512,
            hbuf, 512, 256);
        // 11. f = h @ W2[i] + b2[i] -> abuf    (R x 256)
        gemm_bf16<true, false><<<dim3(RT / 128, 4), 256, 0, stream>>>(
            hbuf, 512, W2 + (size_t)i * 512 * 256, 256, b2 + (size_t)i * 256,
            abuf, 256, 512);
        // 12. x = LN(x + abuf)
        add_ln<<<RT / 4, 256, 0, stream>>>(x, abuf, ln2g + (size_t)i * 256,
                                           ln2b + (size_t)i * 256, x);
    }
    // final LN
    add_ln<<<RT / 4, 256, 0, stream>>>(x, nullptr, lnfg, lnfb, x);
}